// Round 3
// baseline (802.862 us; speedup 1.0000x reference)
//
#include <hip/hip_runtime.h>

#define N_PER 32768
#define STRIDE_ST 68          // padded LDS row stride (words): conflict-free b32 writes + b128 reads
#define KVSZ 288              // per-cloud accum: 256 kv[h][d][e] + 32 ksum[h][d]
#define EPS_LN 1e-5f
#define EPS_Z  1e-6f

// out[j] = b[j] + sum_k h[k] * w[k*32+j]   (w, b wave-uniform -> s_load into SGPRs)
__device__ __forceinline__ void proj32(const float* h, const float* __restrict__ w,
                                       const float* __restrict__ b, float* out) {
#pragma unroll
  for (int j = 0; j < 32; j++) out[j] = b[j];
#pragma unroll
  for (int k = 0; k < 32; k++) {
    float hk = h[k];
#pragma unroll
    for (int j = 0; j < 32; j++) out[j] = fmaf(hk, w[k*32 + j], out[j]);
  }
}

// out[j] += b[j] + sum_k h[k] * w[k*32+j]   (residual-fused projection)
__device__ __forceinline__ void proj32_add(const float* h, const float* __restrict__ w,
                                           const float* __restrict__ b, float* out) {
#pragma unroll
  for (int j = 0; j < 32; j++) out[j] += b[j];
#pragma unroll
  for (int k = 0; k < 32; k++) {
    float hk = h[k];
#pragma unroll
    for (int j = 0; j < 32; j++) out[j] = fmaf(hk, w[k*32 + j], out[j]);
  }
}

// phi(x) = elu(x)+1 = x>0 ? x+1 : exp(x)
__device__ __forceinline__ void phi32(float* a) {
#pragma unroll
  for (int j = 0; j < 32; j++) a[j] = a[j] > 0.f ? a[j] + 1.f : __expf(a[j]);
}

__device__ __forceinline__ void ln32(float* h, const float* __restrict__ g,
                                     const float* __restrict__ b) {
  float mu = 0.f;
#pragma unroll
  for (int j = 0; j < 32; j++) mu += h[j];
  mu *= (1.f / 32.f);
  float var = 0.f;
#pragma unroll
  for (int j = 0; j < 32; j++) { float d = h[j] - mu; var = fmaf(d, d, var); }
  var *= (1.f / 32.f);
  float r = rsqrtf(var + EPS_LN);
#pragma unroll
  for (int j = 0; j < 32; j++) h[j] = (h[j] - mu) * r * g[j] + b[j];
}

// attn[h*8+e] = z_h * sum_d q[h*8+d] * kv[h][d][e],  z_h = 1/(q.ksum_h + eps)
// kvg is wave-uniform global memory (per-cloud summary) -> s_load
__device__ __forceinline__ void attn_part(const float* q, const float* __restrict__ kvg,
                                          float* attn) {
#pragma unroll
  for (int hh = 0; hh < 4; hh++) {
    float dot = 0.f;
#pragma unroll
    for (int d = 0; d < 8; d++) dot = fmaf(q[hh*8 + d], kvg[256 + hh*8 + d], dot);
    float zr = 1.f / (dot + EPS_Z);
#pragma unroll
    for (int e = 0; e < 8; e++) {
      float s = 0.f;
#pragma unroll
      for (int d = 0; d < 8; d++) s = fmaf(q[hh*8 + d], kvg[hh*64 + d*8 + e], s);
      attn[hh*8 + e] = s * zr;
    }
  }
}

// h[j] += bf2[j] + sum_k relu(hid_k) * w2[k*32+j],  hid = h@w1 + bf1 (hidden=64)
__device__ __forceinline__ void ffn32_add(float* h, const float* __restrict__ w1,
                                          const float* __restrict__ b1,
                                          const float* __restrict__ w2,
                                          const float* __restrict__ b2) {
  float hid[64];
#pragma unroll
  for (int j = 0; j < 64; j++) hid[j] = b1[j];
#pragma unroll
  for (int k = 0; k < 32; k++) {
    float hk = h[k];
#pragma unroll
    for (int j = 0; j < 64; j++) hid[j] = fmaf(hk, w1[k*64 + j], hid[j]);
  }
#pragma unroll
  for (int j = 0; j < 32; j++) h[j] += b2[j];
#pragma unroll
  for (int k = 0; k < 64; k++) {
    float hk = fmaxf(hid[k], 0.f);
#pragma unroll
    for (int j = 0; j < 32; j++) h[j] = fmaf(hk, w2[k*32 + j], h[j]);
  }
}

// Per-wave LDS transpose-stage reduction of kv = sum k (x) v and ksum = sum k.
// Lane (d,e) = (lane>>3, lane&7) owns kv[h][d][e] for all 4 heads.
__device__ __forceinline__ void accum_kv(const float* kk, const float* vv,
                                         float* stg, float* blk, float* gkv, int tid) {
  const int lane = tid & 63;
  const int down = lane >> 3;
  const int eown = lane & 7;
  float kvacc[4], ksacc[4];
#pragma unroll
  for (int hh = 0; hh < 4; hh++) {
#pragma unroll
    for (int j = 0; j < 8; j++) {
      stg[j*STRIDE_ST + lane]       = kk[hh*8 + j];
      stg[(8 + j)*STRIDE_ST + lane] = vv[hh*8 + j];
    }
    __syncthreads();
    float acc = 0.f, ks = 0.f;
#pragma unroll
    for (int p = 0; p < 64; p += 4) {
      const float4 kf = *(const float4*)&stg[down*STRIDE_ST + p];
      const float4 vf = *(const float4*)&stg[(8 + eown)*STRIDE_ST + p];
      acc = fmaf(kf.x, vf.x, acc);
      acc = fmaf(kf.y, vf.y, acc);
      acc = fmaf(kf.z, vf.z, acc);
      acc = fmaf(kf.w, vf.w, acc);
      ks += (kf.x + kf.y) + (kf.z + kf.w);
    }
    kvacc[hh] = acc;
    ksacc[hh] = ks;
    __syncthreads();
  }
#pragma unroll
  for (int hh = 0; hh < 4; hh++)
    atomicAdd(&blk[hh*64 + down*8 + eown], kvacc[hh]);
  if (eown == 0) {
#pragma unroll
    for (int hh = 0; hh < 4; hh++)
      atomicAdd(&blk[256 + hh*8 + down], ksacc[hh]);
  }
  __syncthreads();
  for (int i = tid; i < KVSZ; i += 256) atomicAdd(&gkv[i], blk[i]);
}

// K1: embed -> h0 (to d_out), k/v layer0 -> kv accum
__global__ __launch_bounds__(256, 2) void k_embed(
    const float* __restrict__ x, const float* __restrict__ pos,
    const float* __restrict__ w_in, const float* __restrict__ b_in,
    const float* __restrict__ w_pos, const float* __restrict__ b_pos,
    const float* __restrict__ wk, const float* __restrict__ bk,
    const float* __restrict__ wv, const float* __restrict__ bv,
    float* __restrict__ hout, float* __restrict__ gkv) {
  __shared__ __align__(16) float stage[4 * 16 * STRIDE_ST];
  __shared__ float blk[KVSZ];
  const int tid = threadIdx.x;
  for (int i = tid; i < KVSZ; i += 256) blk[i] = 0.f;
  __syncthreads();

  const int pt = blockIdx.x * 256 + tid;
  const int c  = blockIdx.x >> 7;   // 128 blocks per cloud

  float xin[16];
  const float4* xp = (const float4*)(x + (size_t)pt * 16);
#pragma unroll
  for (int q4 = 0; q4 < 4; q4++) {
    float4 t = xp[q4];
    xin[q4*4] = t.x; xin[q4*4+1] = t.y; xin[q4*4+2] = t.z; xin[q4*4+3] = t.w;
  }
  float p0 = pos[(size_t)pt*3], p1 = pos[(size_t)pt*3+1], p2 = pos[(size_t)pt*3+2];

  float h[32];
#pragma unroll
  for (int j = 0; j < 32; j++) h[j] = b_in[j] + b_pos[j];
#pragma unroll
  for (int k = 0; k < 16; k++) {
    float hk = xin[k];
#pragma unroll
    for (int j = 0; j < 32; j++) h[j] = fmaf(hk, w_in[k*32 + j], h[j]);
  }
#pragma unroll
  for (int j = 0; j < 32; j++) {
    h[j] = fmaf(p0, w_pos[j],      h[j]);
    h[j] = fmaf(p1, w_pos[32 + j], h[j]);
    h[j] = fmaf(p2, w_pos[64 + j], h[j]);
  }
  float4* ho = (float4*)(hout + (size_t)pt * 32);
#pragma unroll
  for (int q4 = 0; q4 < 8; q4++) {
    float4 t; t.x = h[q4*4]; t.y = h[q4*4+1]; t.z = h[q4*4+2]; t.w = h[q4*4+3];
    ho[q4] = t;
  }
  float kk[32], vv[32];
  proj32(h, wk, bk, kk);
  phi32(kk);
  proj32(h, wv, bv, vv);
  accum_kv(kk, vv, stage + (tid >> 6) * (16 * STRIDE_ST), blk, gkv + c * KVSZ, tid);
}

// K2: layer-0 attention+FFN (reads/writes hbuf in place), layer-1 k/v -> kv accum
__global__ __launch_bounds__(256, 2) void k_mid(
    const float* __restrict__ wq, const float* __restrict__ bq,
    const float* __restrict__ wo, const float* __restrict__ bo,
    const float* __restrict__ g1, const float* __restrict__ be1,
    const float* __restrict__ w1, const float* __restrict__ bf1,
    const float* __restrict__ w2, const float* __restrict__ bf2,
    const float* __restrict__ g2, const float* __restrict__ be2,
    const float* __restrict__ wkn, const float* __restrict__ bkn,
    const float* __restrict__ wvn, const float* __restrict__ bvn,
    const float* __restrict__ kv_in, float* __restrict__ gkv_out,
    float* __restrict__ hbuf) {
  __shared__ __align__(16) float stage[4 * 16 * STRIDE_ST];
  __shared__ float blk[KVSZ];
  const int tid = threadIdx.x;
  const int c   = blockIdx.x >> 7;
  for (int i = tid; i < KVSZ; i += 256) blk[i] = 0.f;
  __syncthreads();

  const int pt = blockIdx.x * 256 + tid;
  float h[32];
  const float4* hp = (const float4*)(hbuf + (size_t)pt * 32);
#pragma unroll
  for (int q4 = 0; q4 < 8; q4++) {
    float4 t = hp[q4];
    h[q4*4] = t.x; h[q4*4+1] = t.y; h[q4*4+2] = t.z; h[q4*4+3] = t.w;
  }
  float qv[32];
  proj32(h, wq, bq, qv);
  phi32(qv);
  float attn[32];
  attn_part(qv, kv_in + c * KVSZ, attn);
  proj32_add(attn, wo, bo, h);           // h += attn @ wo + bo
  ln32(h, g1, be1);
  ffn32_add(h, w1, bf1, w2, bf2);        // h += ffn(h)
  ln32(h, g2, be2);
  float4* hpw = (float4*)(hbuf + (size_t)pt * 32);
#pragma unroll
  for (int q4 = 0; q4 < 8; q4++) {
    float4 t; t.x = h[q4*4]; t.y = h[q4*4+1]; t.z = h[q4*4+2]; t.w = h[q4*4+3];
    hpw[q4] = t;
  }
  float kk[32], vv[32];
  proj32(h, wkn, bkn, kk);
  phi32(kk);
  proj32(h, wvn, bvn, vv);
  accum_kv(kk, vv, stage + (tid >> 6) * (16 * STRIDE_ST), blk, gkv_out + c * KVSZ, tid);
}

// K3: layer-1 attention+FFN -> final output (in place in hbuf == d_out); no LDS at all
__global__ __launch_bounds__(256, 2) void k_last(
    const float* __restrict__ wq, const float* __restrict__ bq,
    const float* __restrict__ wo, const float* __restrict__ bo,
    const float* __restrict__ g1, const float* __restrict__ be1,
    const float* __restrict__ w1, const float* __restrict__ bf1,
    const float* __restrict__ w2, const float* __restrict__ bf2,
    const float* __restrict__ g2, const float* __restrict__ be2,
    const float* __restrict__ kv_in, float* __restrict__ hbuf) {
  const int tid = threadIdx.x;
  const int c   = blockIdx.x >> 7;
  const int pt  = blockIdx.x * 256 + tid;
  float h[32];
  const float4* hp = (const float4*)(hbuf + (size_t)pt * 32);
#pragma unroll
  for (int q4 = 0; q4 < 8; q4++) {
    float4 t = hp[q4];
    h[q4*4] = t.x; h[q4*4+1] = t.y; h[q4*4+2] = t.z; h[q4*4+3] = t.w;
  }
  float qv[32];
  proj32(h, wq, bq, qv);
  phi32(qv);
  float attn[32];
  attn_part(qv, kv_in + c * KVSZ, attn);
  proj32_add(attn, wo, bo, h);
  ln32(h, g1, be1);
  ffn32_add(h, w1, bf1, w2, bf2);
  ln32(h, g2, be2);
  float4* hpw = (float4*)(hbuf + (size_t)pt * 32);
#pragma unroll
  for (int q4 = 0; q4 < 8; q4++) {
    float4 t; t.x = h[q4*4]; t.y = h[q4*4+1]; t.z = h[q4*4+2]; t.w = h[q4*4+3];
    hpw[q4] = t;
  }
}

extern "C" void kernel_launch(void* const* d_in, const int* in_sizes, int n_in,
                              void* d_out, int out_size, void* d_ws, size_t ws_size,
                              hipStream_t stream) {
  (void)in_sizes; (void)n_in; (void)out_size; (void)ws_size;
  const float* x     = (const float*)d_in[0];
  const float* pos   = (const float*)d_in[1];
  // d_in[2] = batch (arange//N_PER) -- identity mapping, unused
  const float* w_in  = (const float*)d_in[3];
  const float* b_in  = (const float*)d_in[4];
  const float* w_pos = (const float*)d_in[5];
  const float* b_pos = (const float*)d_in[6];
  const float* wq  = (const float*)d_in[7];
  const float* bq  = (const float*)d_in[8];
  const float* wk  = (const float*)d_in[9];
  const float* bk  = (const float*)d_in[10];
  const float* wv  = (const float*)d_in[11];
  const float* bv  = (const float*)d_in[12];
  const float* wo  = (const float*)d_in[13];
  const float* bo  = (const float*)d_in[14];
  const float* g1  = (const float*)d_in[15];
  const float* be1 = (const float*)d_in[16];
  const float* w1  = (const float*)d_in[17];
  const float* bf1 = (const float*)d_in[18];
  const float* w2  = (const float*)d_in[19];
  const float* bf2 = (const float*)d_in[20];
  const float* g2  = (const float*)d_in[21];
  const float* be2 = (const float*)d_in[22];
  float* out   = (float*)d_out;
  float* kvbuf = (float*)d_ws;   // 2 layers * 16 clouds * 288 floats = 36 KB

  hipMemsetAsync(kvbuf, 0, 2 * 16 * KVSZ * sizeof(float), stream);
  dim3 grid(2048), block(256);
  k_embed<<<grid, block, 0, stream>>>(x, pos, w_in, b_in, w_pos, b_pos,
                                      wk, bk, wv, bv, out, kvbuf);
  k_mid<<<grid, block, 0, stream>>>(wq, bq, wo, bo, g1, be1, w1, bf1, w2, bf2, g2, be2,
                                    wk + 1024, bk + 32, wv + 1024, bv + 32,
                                    kvbuf, kvbuf + 16 * KVSZ, out);
  k_last<<<grid, block, 0, stream>>>(wq + 1024, bq + 32, wo + 1024, bo + 32,
                                     g1 + 32, be1 + 32, w1 + 2048, bf1 + 64,
                                     w2 + 2048, bf2 + 32, g2 + 32, be2 + 32,
                                     kvbuf + 16 * KVSZ, out);
}

// Round 4
// 388.595 us; speedup vs baseline: 2.0661x; 2.0661x over previous
//
#include <hip/hip_runtime.h>

#define KVSZ 288            // per-cloud: 256 kv[h][d][e] + 32 ksum[feat]
#define EPS_LN 1e-5f
#define EPS_Z  1e-6f
#define TS 72               // wave tile row stride in bf16 elems (144 B, 16B-aligned rows)

typedef __attribute__((ext_vector_type(8))) short bf16x8;   // MFMA A/B frag (4 VGPR)
typedef __attribute__((ext_vector_type(4))) float f32x4;    // MFMA C/D frag

#define MFMA(a, b, c) __builtin_amdgcn_mfma_f32_16x16x32_bf16(a, b, c, 0, 0, 0)

__device__ __forceinline__ short f2bf(float f) {            // fp32 -> bf16 RNE
  union { float f; unsigned u; } x; x.f = f;
  unsigned r = x.u + 0x7fff + ((x.u >> 16) & 1);
  return (short)(r >> 16);
}
__device__ __forceinline__ void lds_fence() { asm volatile("s_waitcnt lgkmcnt(0)" ::: "memory"); }
__device__ __forceinline__ float phi(float x) { return x > 0.f ? x + 1.f : __expf(x); }

// B-frag: lane (quad,m) holds W[k0+j][n], j=0..7 (W row-major K x ld)
__device__ __forceinline__ bf16x8 load_bfrag(const float* __restrict__ W, int ld, int k0, int n) {
  bf16x8 b;
#pragma unroll
  for (int j = 0; j < 8; j++) b[j] = f2bf(W[(k0 + j) * ld + n]);
  return b;
}

// C-layout (32-col) -> wave tile bf16, cols 0..31
__device__ __forceinline__ void store_c32(unsigned short* tw, int mt, int quad, int m,
                                          f32x4 a0, f32x4 a1) {
#pragma unroll
  for (int r = 0; r < 4; r++) {
    int row = mt * 16 + quad * 4 + r;
    tw[row * TS + m]      = (unsigned short)f2bf(a0[r]);
    tw[row * TS + 16 + m] = (unsigned short)f2bf(a1[r]);
  }
}

// LayerNorm over 32 features in C-layout: rows are per-(r), features spread over
// 16 lanes x 2 accs; butterfly over low 4 lane bits reduces within the row group.
__device__ __forceinline__ void ln_c(f32x4& a0, f32x4& a1, float gg0, float gg1,
                                     float bb0, float bb1) {
#pragma unroll
  for (int r = 0; r < 4; r++) {
    float s = a0[r] + a1[r];
    s += __shfl_xor(s, 1); s += __shfl_xor(s, 2); s += __shfl_xor(s, 4); s += __shfl_xor(s, 8);
    float mu = s * (1.f / 32.f);
    float d0 = a0[r] - mu, d1 = a1[r] - mu;
    float vv = d0 * d0 + d1 * d1;
    vv += __shfl_xor(vv, 1); vv += __shfl_xor(vv, 2); vv += __shfl_xor(vv, 4); vv += __shfl_xor(vv, 8);
    float rstd = rsqrtf(vv * (1.f / 32.f) + EPS_LN);
    a0[r] = d0 * rstd * gg0 + bb0;
    a1[r] = d1 * rstd * gg1 + bb1;
  }
}

// attention + FFN for one layer, per wave (64 points, 4 m-tiles).
// hc0/hc1: h in C-layout (updated in place to layer output). hA: h in A-layout.
__device__ __forceinline__ void layer_core(
    f32x4* hc0, f32x4* hc1, const bf16x8* hA, unsigned short* tw, int quad, int m,
    const float* __restrict__ wq, const float* __restrict__ bq,
    const float* __restrict__ wo, const float* __restrict__ bo,
    const float* __restrict__ g1, const float* __restrict__ be1,
    const float* __restrict__ w1, const float* __restrict__ bf1,
    const float* __restrict__ w2, const float* __restrict__ bf2,
    const float* __restrict__ g2, const float* __restrict__ be2,
    const float* __restrict__ kvg) {
  const int k0 = quad * 8;
  // ---- q = phi(h @ wq + bq), C-layout
  bf16x8 wb0 = load_bfrag(wq, 32, k0, m);
  bf16x8 wb1 = load_bfrag(wq, 32, k0, 16 + m);
  float bc0 = bq[m], bc1 = bq[16 + m];
  f32x4 q0[4], q1[4];
#pragma unroll
  for (int mt = 0; mt < 4; mt++) {
    f32x4 i0 = {bc0, bc0, bc0, bc0}, i1 = {bc1, bc1, bc1, bc1};
    q0[mt] = MFMA(hA[mt], wb0, i0);
    q1[mt] = MFMA(hA[mt], wb1, i1);
  }
#pragma unroll
  for (int mt = 0; mt < 4; mt++)
#pragma unroll
    for (int r = 0; r < 4; r++) { q0[mt][r] = phi(q0[mt][r]); q1[mt][r] = phi(q1[mt][r]); }
  // ---- attnraw = q @ kv (block-diagonal heads): q via tile to A-layout
#pragma unroll
  for (int mt = 0; mt < 4; mt++) store_c32(tw, mt, quad, m, q0[mt], q1[mt]);
  lds_fence();
  bf16x8 kvb0, kvb1;
  {
    bool on0 = (quad == (m >> 3));        // head(col n=m)    == head(k-range)=quad
    bool on1 = (quad == 2 + (m >> 3));    // head(col n=16+m)
#pragma unroll
    for (int j = 0; j < 8; j++) {
      float v0 = on0 ? kvg[quad * 64 + j * 8 + (m & 7)] : 0.f;
      float v1 = on1 ? kvg[quad * 64 + j * 8 + (m & 7)] : 0.f;
      kvb0[j] = f2bf(v0); kvb1[j] = f2bf(v1);
    }
  }
  f32x4 at0[4], at1[4];
#pragma unroll
  for (int mt = 0; mt < 4; mt++) {
    bf16x8 aq = *(const bf16x8*)&tw[(mt * 16 + m) * TS + k0];
    f32x4 zz = {0.f, 0.f, 0.f, 0.f};
    at0[mt] = MFMA(aq, kvb0, zz);
    at1[mt] = MFMA(aq, kvb1, zz);
  }
  // ---- z = 1/(q . ksum + eps) from fp32 q C-regs; apply to attnraw
  {
    float ks0 = kvg[256 + m], ks1 = kvg[272 + m];
#pragma unroll
    for (int mt = 0; mt < 4; mt++)
#pragma unroll
      for (int r = 0; r < 4; r++) {
        float p0 = q0[mt][r] * ks0, p1 = q1[mt][r] * ks1;
        p0 += __shfl_xor(p0, 1); p0 += __shfl_xor(p0, 2); p0 += __shfl_xor(p0, 4);
        p1 += __shfl_xor(p1, 1); p1 += __shfl_xor(p1, 2); p1 += __shfl_xor(p1, 4);
        at0[mt][r] *= 1.f / (p0 + EPS_Z);
        at1[mt][r] *= 1.f / (p1 + EPS_Z);
      }
  }
  // ---- h += attn @ wo + bo
  lds_fence();
#pragma unroll
  for (int mt = 0; mt < 4; mt++) store_c32(tw, mt, quad, m, at0[mt], at1[mt]);
  lds_fence();
  wb0 = load_bfrag(wo, 32, k0, m);
  wb1 = load_bfrag(wo, 32, k0, 16 + m);
  bc0 = bo[m]; bc1 = bo[16 + m];
#pragma unroll
  for (int mt = 0; mt < 4; mt++) {
    bf16x8 aa = *(const bf16x8*)&tw[(mt * 16 + m) * TS + k0];
    f32x4 i0 = hc0[mt], i1 = hc1[mt];
#pragma unroll
    for (int r = 0; r < 4; r++) { i0[r] += bc0; i1[r] += bc1; }
    hc0[mt] = MFMA(aa, wb0, i0);
    hc1[mt] = MFMA(aa, wb1, i1);
  }
  // ---- LN1
  {
    float gg0 = g1[m], gg1 = g1[16 + m], bb0 = be1[m], bb1 = be1[16 + m];
#pragma unroll
    for (int mt = 0; mt < 4; mt++) ln_c(hc0[mt], hc1[mt], gg0, gg1, bb0, bb1);
  }
  // ---- FFN: hid = relu(h @ w1 + bf1) [64]; h += hid @ w2 + bf2  (per m-tile)
  lds_fence();
#pragma unroll
  for (int mt = 0; mt < 4; mt++) store_c32(tw, mt, quad, m, hc0[mt], hc1[mt]);
  lds_fence();
  bf16x8 w1f[4]; float b1c[4];
#pragma unroll
  for (int nt = 0; nt < 4; nt++) {
    w1f[nt] = load_bfrag(w1, 64, k0, nt * 16 + m);
    b1c[nt] = bf1[nt * 16 + m];
  }
  bf16x8 w2f[4];
#pragma unroll
  for (int kc = 0; kc < 2; kc++)
#pragma unroll
    for (int nt = 0; nt < 2; nt++)
      w2f[kc * 2 + nt] = load_bfrag(w2, 32, kc * 32 + k0, nt * 16 + m);
  float b2c0 = bf2[m], b2c1 = bf2[16 + m];
#pragma unroll
  for (int mt = 0; mt < 4; mt++) {
    bf16x8 ah = *(const bf16x8*)&tw[(mt * 16 + m) * TS + k0];   // hln A-frag (this mt)
    f32x4 hd[4];
#pragma unroll
    for (int nt = 0; nt < 4; nt++) {
      f32x4 ini = {b1c[nt], b1c[nt], b1c[nt], b1c[nt]};
      hd[nt] = MFMA(ah, w1f[nt], ini);
    }
    lds_fence();
#pragma unroll
    for (int nt = 0; nt < 4; nt++)
#pragma unroll
      for (int r = 0; r < 4; r++)
        tw[(mt * 16 + quad * 4 + r) * TS + nt * 16 + m] =
            (unsigned short)f2bf(fmaxf(hd[nt][r], 0.f));   // relu(hid), cols 0..63 (this mt only)
    lds_fence();
    f32x4 o0 = hc0[mt], o1 = hc1[mt];
#pragma unroll
    for (int r = 0; r < 4; r++) { o0[r] += b2c0; o1[r] += b2c1; }
#pragma unroll
    for (int kc = 0; kc < 2; kc++) {
      bf16x8 a2 = *(const bf16x8*)&tw[(mt * 16 + m) * TS + kc * 32 + k0];
      o0 = MFMA(a2, w2f[kc * 2 + 0], o0);
      o1 = MFMA(a2, w2f[kc * 2 + 1], o1);
    }
    hc0[mt] = o0; hc1[mt] = o1;
  }
  // ---- LN2
  {
    float gg0 = g2[m], gg1 = g2[16 + m], bb0 = be2[m], bb1 = be2[16 + m];
#pragma unroll
    for (int mt = 0; mt < 4; mt++) ln_c(hc0[mt], hc1[mt], gg0, gg1, bb0, bb1);
  }
}

// kn = phi(h@wk+bk), vn = h@wv+bv, then kv += kn^T @ vn (per-head diag) and ksum += sum kn.
__device__ __forceinline__ void kv_stage(
    const f32x4* hc0, const f32x4* hc1, unsigned short* tw, float* blk, int quad, int m,
    const float* __restrict__ wk, const float* __restrict__ bk,
    const float* __restrict__ wv, const float* __restrict__ bv) {
  const int k0 = quad * 8;
  lds_fence();
#pragma unroll
  for (int mt = 0; mt < 4; mt++) store_c32(tw, mt, quad, m, hc0[mt], hc1[mt]);
  lds_fence();
  bf16x8 ahf[4];
#pragma unroll
  for (int mt = 0; mt < 4; mt++) ahf[mt] = *(const bf16x8*)&tw[(mt * 16 + m) * TS + k0];
  bf16x8 wkb0 = load_bfrag(wk, 32, k0, m), wkb1 = load_bfrag(wk, 32, k0, 16 + m);
  bf16x8 wvb0 = load_bfrag(wv, 32, k0, m), wvb1 = load_bfrag(wv, 32, k0, 16 + m);
  float bkc0 = bk[m], bkc1 = bk[16 + m], bvc0 = bv[m], bvc1 = bv[16 + m];
  f32x4 kn0[4], kn1[4], vn0[4], vn1[4];
#pragma unroll
  for (int mt = 0; mt < 4; mt++) {
    f32x4 ik0 = {bkc0, bkc0, bkc0, bkc0}, ik1 = {bkc1, bkc1, bkc1, bkc1};
    f32x4 iv0 = {bvc0, bvc0, bvc0, bvc0}, iv1 = {bvc1, bvc1, bvc1, bvc1};
    kn0[mt] = MFMA(ahf[mt], wkb0, ik0);
    kn1[mt] = MFMA(ahf[mt], wkb1, ik1);
    vn0[mt] = MFMA(ahf[mt], wvb0, iv0);
    vn1[mt] = MFMA(ahf[mt], wvb1, iv1);
  }
#pragma unroll
  for (int mt = 0; mt < 4; mt++)
#pragma unroll
    for (int r = 0; r < 4; r++) { kn0[mt][r] = phi(kn0[mt][r]); kn1[mt][r] = phi(kn1[mt][r]); }
  // ksum over this wave's 64 points (sum over r,mt in-lane, then over quads)
  float s0 = 0.f, s1 = 0.f;
#pragma unroll
  for (int mt = 0; mt < 4; mt++)
#pragma unroll
    for (int r = 0; r < 4; r++) { s0 += kn0[mt][r]; s1 += kn1[mt][r]; }
  s0 += __shfl_xor(s0, 16); s0 += __shfl_xor(s0, 32);
  s1 += __shfl_xor(s1, 16); s1 += __shfl_xor(s1, 32);
  if (quad == 0) { atomicAdd(&blk[256 + m], s0); atomicAdd(&blk[272 + m], s1); }
  // store kn (cols 0..31) and vn (cols 32..63)
  lds_fence();
#pragma unroll
  for (int mt = 0; mt < 4; mt++) {
    store_c32(tw, mt, quad, m, kn0[mt], kn1[mt]);
#pragma unroll
    for (int r = 0; r < 4; r++) {
      int row = mt * 16 + quad * 4 + r;
      tw[row * TS + 32 + m] = (unsigned short)f2bf(vn0[mt][r]);
      tw[row * TS + 48 + m] = (unsigned short)f2bf(vn1[mt][r]);
    }
  }
  lds_fence();
  // kv = kn^T @ vn via MFMA: A[d][point] gathered from tile, B[point][e] likewise.
#pragma unroll
  for (int tp = 0; tp < 2; tp++) {            // diag feature-tile pairs (heads 0,1 | 2,3)
    f32x4 acc = {0.f, 0.f, 0.f, 0.f};
#pragma unroll
    for (int kc = 0; kc < 2; kc++) {
      bf16x8 ak, bv8;
#pragma unroll
      for (int j = 0; j < 8; j++) {
        int prow = (kc * 32 + k0 + j) * TS;
        ak[j]  = (short)tw[prow + tp * 16 + m];
        bv8[j] = (short)tw[prow + 32 + tp * 16 + m];
      }
      acc = MFMA(ak, bv8, acc);
    }
    if ((quad >> 1) == (m >> 3)) {            // same-head (diag 8x8 block) elements only
      int head = tp * 2 + (quad >> 1);
      int dbase = (quad & 1) * 4;
#pragma unroll
      for (int r = 0; r < 4; r++)
        atomicAdd(&blk[head * 64 + (dbase + r) * 8 + (m & 7)], acc[r]);
    }
  }
}

// K1: embed -> h0 (to d_out), layer-0 kn/vn -> kv accum
__global__ __launch_bounds__(256) void k_embed(
    const float* __restrict__ x, const float* __restrict__ pos,
    const float* __restrict__ w_in, const float* __restrict__ b_in,
    const float* __restrict__ w_pos, const float* __restrict__ b_pos,
    const float* __restrict__ wk, const float* __restrict__ bk,
    const float* __restrict__ wv, const float* __restrict__ bv,
    float* __restrict__ hout, float* __restrict__ gkv) {
  __shared__ __align__(16) unsigned short tile[4 * 64 * TS];
  __shared__ float blk[KVSZ];
  const int tid = threadIdx.x;
  const int wv_ = tid >> 6, lane = tid & 63, quad = lane >> 4, m = lane & 15;
  unsigned short* tw = tile + wv_ * 64 * TS;
  for (int i = tid; i < KVSZ; i += 256) blk[i] = 0.f;
  __syncthreads();
  const int wbase = blockIdx.x * 256 + wv_ * 64;
  const int cloud = blockIdx.x >> 7;
  const int k0 = quad * 8;
  // A-frags for [x(16) | pos(3) | 0...]: quads 0,1 = x; quad 2 = pos; quad 3 = 0
  bf16x8 aE[4];
#pragma unroll
  for (int mt = 0; mt < 4; mt++) {
    int p = wbase + mt * 16 + m;
    bf16x8 a;
#pragma unroll
    for (int j = 0; j < 8; j++) a[j] = 0;
    if (quad < 2) {
      const float4* xp = (const float4*)(x + (size_t)p * 16 + quad * 8);
      float4 t0 = xp[0], t1 = xp[1];
      a[0] = f2bf(t0.x); a[1] = f2bf(t0.y); a[2] = f2bf(t0.z); a[3] = f2bf(t0.w);
      a[4] = f2bf(t1.x); a[5] = f2bf(t1.y); a[6] = f2bf(t1.z); a[7] = f2bf(t1.w);
    } else if (quad == 2) {
      const float* pp = pos + (size_t)p * 3;
      a[0] = f2bf(pp[0]); a[1] = f2bf(pp[1]); a[2] = f2bf(pp[2]);
    }
    aE[mt] = a;
  }
  // B-frags for [w_in ; w_pos ; 0]
  bf16x8 we0, we1;
#pragma unroll
  for (int j = 0; j < 8; j++) { we0[j] = 0; we1[j] = 0; }
  if (quad < 2) {
#pragma unroll
    for (int j = 0; j < 8; j++) {
      we0[j] = f2bf(w_in[(k0 + j) * 32 + m]);
      we1[j] = f2bf(w_in[(k0 + j) * 32 + 16 + m]);
    }
  } else if (quad == 2) {
#pragma unroll
    for (int j = 0; j < 3; j++) {
      we0[j] = f2bf(w_pos[j * 32 + m]);
      we1[j] = f2bf(w_pos[j * 32 + 16 + m]);
    }
  }
  float bc0 = b_in[m] + b_pos[m], bc1 = b_in[16 + m] + b_pos[16 + m];
  f32x4 hc0[4], hc1[4];
#pragma unroll
  for (int mt = 0; mt < 4; mt++) {
    f32x4 i0 = {bc0, bc0, bc0, bc0}, i1 = {bc1, bc1, bc1, bc1};
    hc0[mt] = MFMA(aE[mt], we0, i0);
    hc1[mt] = MFMA(aE[mt], we1, i1);
  }
  // store h0 (C-layout scatter; 16-lane groups hit 64B segments)
#pragma unroll
  for (int mt = 0; mt < 4; mt++)
#pragma unroll
    for (int r = 0; r < 4; r++) {
      int p = wbase + mt * 16 + quad * 4 + r;
      hout[(size_t)p * 32 + m]      = hc0[mt][r];
      hout[(size_t)p * 32 + 16 + m] = hc1[mt][r];
    }
  kv_stage(hc0, hc1, tw, blk, quad, m, wk, bk, wv, bv);
  __syncthreads();
  float* g = gkv + cloud * KVSZ;
  for (int i = tid; i < KVSZ; i += 256) atomicAdd(&g[i], blk[i]);
}

// K2: layer-0 attn+FFN (in place on hbuf), layer-1 kn/vn -> kv accum
__global__ __launch_bounds__(256) void k_mid(
    const float* __restrict__ wq, const float* __restrict__ bq,
    const float* __restrict__ wo, const float* __restrict__ bo,
    const float* __restrict__ g1, const float* __restrict__ be1,
    const float* __restrict__ w1, const float* __restrict__ bf1,
    const float* __restrict__ w2, const float* __restrict__ bf2,
    const float* __restrict__ g2, const float* __restrict__ be2,
    const float* __restrict__ wkn, const float* __restrict__ bkn,
    const float* __restrict__ wvn, const float* __restrict__ bvn,
    const float* __restrict__ kv_in, float* __restrict__ gkv_out,
    float* __restrict__ hbuf) {
  __shared__ __align__(16) unsigned short tile[4 * 64 * TS];
  __shared__ float blk[KVSZ];
  const int tid = threadIdx.x;
  const int wv_ = tid >> 6, lane = tid & 63, quad = lane >> 4, m = lane & 15;
  unsigned short* tw = tile + wv_ * 64 * TS;
  for (int i = tid; i < KVSZ; i += 256) blk[i] = 0.f;
  __syncthreads();
  const int wbase = blockIdx.x * 256 + wv_ * 64;
  const int cloud = blockIdx.x >> 7;
  const int k0 = quad * 8;
  // dual-load h: C-layout fp32 regs + A-layout bf16 frags
  f32x4 hc0[4], hc1[4];
#pragma unroll
  for (int mt = 0; mt < 4; mt++)
#pragma unroll
    for (int r = 0; r < 4; r++) {
      int p = wbase + mt * 16 + quad * 4 + r;
      hc0[mt][r] = hbuf[(size_t)p * 32 + m];
      hc1[mt][r] = hbuf[(size_t)p * 32 + 16 + m];
    }
  bf16x8 hA[4];
#pragma unroll
  for (int mt = 0; mt < 4; mt++) {
    const float* hp = hbuf + (size_t)(wbase + mt * 16 + m) * 32 + k0;
    float4 u0 = *(const float4*)hp, u1 = *(const float4*)(hp + 4);
    bf16x8 a;
    a[0] = f2bf(u0.x); a[1] = f2bf(u0.y); a[2] = f2bf(u0.z); a[3] = f2bf(u0.w);
    a[4] = f2bf(u1.x); a[5] = f2bf(u1.y); a[6] = f2bf(u1.z); a[7] = f2bf(u1.w);
    hA[mt] = a;
  }
  layer_core(hc0, hc1, hA, tw, quad, m, wq, bq, wo, bo, g1, be1, w1, bf1, w2, bf2,
             g2, be2, kv_in + cloud * KVSZ);
#pragma unroll
  for (int mt = 0; mt < 4; mt++)
#pragma unroll
    for (int r = 0; r < 4; r++) {
      int p = wbase + mt * 16 + quad * 4 + r;
      hbuf[(size_t)p * 32 + m]      = hc0[mt][r];
      hbuf[(size_t)p * 32 + 16 + m] = hc1[mt][r];
    }
  kv_stage(hc0, hc1, tw, blk, quad, m, wkn, bkn, wvn, bvn);
  __syncthreads();
  float* g = gkv_out + cloud * KVSZ;
  for (int i = tid; i < KVSZ; i += 256) atomicAdd(&g[i], blk[i]);
}

// K3: layer-1 attn+FFN -> final output (in place on hbuf == d_out)
__global__ __launch_bounds__(256) void k_last(
    const float* __restrict__ wq, const float* __restrict__ bq,
    const float* __restrict__ wo, const float* __restrict__ bo,
    const float* __restrict__ g1, const float* __restrict__ be1,
    const float* __restrict__ w1, const float* __restrict__ bf1,
    const float* __restrict__ w2, const float* __restrict__ bf2,
    const float* __restrict__ g2, const float* __restrict__ be2,
    const float* __restrict__ kv_in, float* __restrict__ hbuf) {
  __shared__ __align__(16) unsigned short tile[4 * 64 * TS];
  const int tid = threadIdx.x;
  const int wv_ = tid >> 6, lane = tid & 63, quad = lane >> 4, m = lane & 15;
  unsigned short* tw = tile + wv_ * 64 * TS;
  const int wbase = blockIdx.x * 256 + wv_ * 64;
  const int cloud = blockIdx.x >> 7;
  const int k0 = quad * 8;
  f32x4 hc0[4], hc1[4];
#pragma unroll
  for (int mt = 0; mt < 4; mt++)
#pragma unroll
    for (int r = 0; r < 4; r++) {
      int p = wbase + mt * 16 + quad * 4 + r;
      hc0[mt][r] = hbuf[(size_t)p * 32 + m];
      hc1[mt][r] = hbuf[(size_t)p * 32 + 16 + m];
    }
  bf16x8 hA[4];
#pragma unroll
  for (int mt = 0; mt < 4; mt++) {
    const float* hp = hbuf + (size_t)(wbase + mt * 16 + m) * 32 + k0;
    float4 u0 = *(const float4*)hp, u1 = *(const float4*)(hp + 4);
    bf16x8 a;
    a[0] = f2bf(u0.x); a[1] = f2bf(u0.y); a[2] = f2bf(u0.z); a[3] = f2bf(u0.w);
    a[4] = f2bf(u1.x); a[5] = f2bf(u1.y); a[6] = f2bf(u1.z); a[7] = f2bf(u1.w);
    hA[mt] = a;
  }
  layer_core(hc0, hc1, hA, tw, quad, m, wq, bq, wo, bo, g1, be1, w1, bf1, w2, bf2,
             g2, be2, kv_in + cloud * KVSZ);
#pragma unroll
  for (int mt = 0; mt < 4; mt++)
#pragma unroll
    for (int r = 0; r < 4; r++) {
      int p = wbase + mt * 16 + quad * 4 + r;
      hbuf[(size_t)p * 32 + m]      = hc0[mt][r];
      hbuf[(size_t)p * 32 + 16 + m] = hc1[mt][r];
    }
}

extern "C" void kernel_launch(void* const* d_in, const int* in_sizes, int n_in,
                              void* d_out, int out_size, void* d_ws, size_t ws_size,
                              hipStream_t stream) {
  (void)in_sizes; (void)n_in; (void)out_size; (void)ws_size;
  const float* x     = (const float*)d_in[0];
  const float* pos   = (const float*)d_in[1];
  // d_in[2] = batch (arange // N_PER): identity mapping, unused
  const float* w_in  = (const float*)d_in[3];
  const float* b_in  = (const float*)d_in[4];
  const float* w_pos = (const float*)d_in[5];
  const float* b_pos = (const float*)d_in[6];
  const float* wq  = (const float*)d_in[7];
  const float* bq  = (const float*)d_in[8];
  const float* wk  = (const float*)d_in[9];
  const float* bk  = (const float*)d_in[10];
  const float* wv  = (const float*)d_in[11];
  const float* bv  = (const float*)d_in[12];
  const float* wo  = (const float*)d_in[13];
  const float* bo  = (const float*)d_in[14];
  const float* g1  = (const float*)d_in[15];
  const float* be1 = (const float*)d_in[16];
  const float* w1  = (const float*)d_in[17];
  const float* bf1 = (const float*)d_in[18];
  const float* w2  = (const float*)d_in[19];
  const float* bf2 = (const float*)d_in[20];
  const float* g2  = (const float*)d_in[21];
  const float* be2 = (const float*)d_in[22];
  float* out   = (float*)d_out;
  float* kvbuf = (float*)d_ws;   // 2 layers * 16 clouds * 288 floats

  hipMemsetAsync(kvbuf, 0, 2 * 16 * KVSZ * sizeof(float), stream);
  dim3 grid(2048), block(256);
  k_embed<<<grid, block, 0, stream>>>(x, pos, w_in, b_in, w_pos, b_pos,
                                      wk, bk, wv, bv, out, kvbuf);
  k_mid<<<grid, block, 0, stream>>>(wq, bq, wo, bo, g1, be1, w1, bf1, w2, bf2, g2, be2,
                                    wk + 1024, bk + 32, wv + 1024, bv + 32,
                                    kvbuf, kvbuf + 16 * KVSZ, out);
  k_last<<<grid, block, 0, stream>>>(wq + 1024, bq + 32, wo + 1024, bo + 32,
                                     g1 + 32, be1 + 32, w1 + 2048, bf1 + 64,
                                     w2 + 2048, bf2 + 32, g2 + 32, be2 + 32,
                                     kvbuf + 16 * KVSZ, out);
}

// Round 5
// 383.842 us; speedup vs baseline: 2.0916x; 1.0124x over previous
//
#include <hip/hip_runtime.h>

#define KVSZ 288            // per-cloud: 256 kv[h][d][e] + 32 ksum[feat]
#define EPS_LN 1e-5f
#define EPS_Z  1e-6f

typedef __attribute__((ext_vector_type(8))) short bf16x8;   // MFMA A/B frag (4 VGPR)
typedef __attribute__((ext_vector_type(4))) float f32x4;    // MFMA C/D frag

#define MFMA(a, b, c) __builtin_amdgcn_mfma_f32_16x16x32_bf16(a, b, c, 0, 0, 0)

// staged-weight element offsets (k_mid / k_last layout)
#define WQ  0
#define WO  1024
#define KVM 2048
#define W1  3072
#define W2  5120
#define WKN 7168
#define WVN 8192

__device__ __forceinline__ unsigned short f2bf(float f) {   // fp32 -> bf16 RNE
  union { float f; unsigned u; } x; x.f = f;
  unsigned r = x.u + 0x7fff + ((x.u >> 16) & 1);
  return (unsigned short)(r >> 16);
}

// pack 2 fp32 -> 2 bf16 in one u32 (low = a). HW packed cvt when available.
__device__ __forceinline__ unsigned pkbf(float a, float b) {
#if __has_builtin(__builtin_amdgcn_cvt_pk_bf16_f32)
  typedef __attribute__((ext_vector_type(2))) __bf16 bf16x2_t;
  bf16x2_t v = __builtin_amdgcn_cvt_pk_bf16_f32(a, b);
  return __builtin_bit_cast(unsigned, v);
#else
  return (unsigned)f2bf(a) | ((unsigned)f2bf(b) << 16);
#endif
}

__device__ __forceinline__ void lds_fence() { asm volatile("s_waitcnt lgkmcnt(0)" ::: "memory"); }
__device__ __forceinline__ float phi(float x) { return x > 0.f ? x + 1.f : __expf(x); }

// ---- cooperative weight staging: dst[n*32+kp] = W[L(kp)][n], L = packed perm ----
__device__ __forceinline__ void stage_pk32(unsigned short* dst, const float* __restrict__ W,
                                           int N, int tid) {
  for (int i = tid; i < 32 * N; i += 256) {
    int n = i >> 5, kp = i & 31;
    int kl = (kp & 1) * 16 + (kp >> 1);
    dst[i] = f2bf(W[kl * N + n]);
  }
}
// w2: K=64 packed perm, N=32: dst[n*64+kp]
__device__ __forceinline__ void stage_pk64(unsigned short* dst, const float* __restrict__ W,
                                           int tid) {
  for (int i = tid; i < 64 * 32; i += 256) {
    int n = i >> 6, kp = i & 63;
    int kl = (kp >> 5) * 32 + (kp & 1) * 16 + ((kp & 31) >> 1);
    dst[i] = f2bf(W[kl * 32 + n]);
  }
}
// block-diagonal kv summary matrix: B[klog][n] = same-head ? kv[h][d][e] : 0
__device__ __forceinline__ void stage_kvm(unsigned short* dst, const float* __restrict__ kvg,
                                          int tid) {
  for (int i = tid; i < 1024; i += 256) {
    int n = i >> 5, kp = i & 31;
    int kl = (kp & 1) * 16 + (kp >> 1);
    float v = ((kl >> 3) == (n >> 3)) ? kvg[(n >> 3) * 64 + (kl & 7) * 8 + (n & 7)] : 0.f;
    dst[i] = f2bf(v);
  }
}

// LayerNorm over 32 features in C-layout (16 lanes x 2 accs), butterfly over low 4 bits.
__device__ __forceinline__ void ln_c(f32x4& a0, f32x4& a1, float gg0, float gg1,
                                     float bb0, float bb1) {
#pragma unroll
  for (int r = 0; r < 4; r++) {
    float s = a0[r] + a1[r];
    s += __shfl_xor(s, 1); s += __shfl_xor(s, 2); s += __shfl_xor(s, 4); s += __shfl_xor(s, 8);
    float mu = s * (1.f / 32.f);
    float d0 = a0[r] - mu, d1 = a1[r] - mu;
    float vv = d0 * d0 + d1 * d1;
    vv += __shfl_xor(vv, 1); vv += __shfl_xor(vv, 2); vv += __shfl_xor(vv, 4); vv += __shfl_xor(vv, 8);
    float rstd = rsqrtf(vv * (1.f / 32.f) + EPS_LN);
    a0[r] = d0 * rstd * gg0 + bb0;
    a1[r] = d1 * rstd * gg1 + bb1;
  }
}

// attention + FFN for one layer; per-wave mini tiles: mt_t 16x40 @ tw, hid_t 16x72 @ tw+640
__device__ __forceinline__ void layer_core(
    f32x4* hc0, f32x4* hc1, const bf16x8* hA, unsigned short* tw,
    const unsigned short* ws, int quad, int m,
    const float* __restrict__ bq, const float* __restrict__ bo,
    const float* __restrict__ g1, const float* __restrict__ be1,
    const float* __restrict__ bf1, const float* __restrict__ bf2,
    const float* __restrict__ g2, const float* __restrict__ be2,
    const float* __restrict__ kvg) {
  const int k0 = quad * 8;
  unsigned short* mt_t  = tw;        // 16 rows x 40
  unsigned short* hid_t = tw + 640;  // 16 rows x 72
  // ---- q = phi(h @ wq + bq)
  bf16x8 wb0 = *(const bf16x8*)(ws + WQ + m * 32 + k0);
  bf16x8 wb1 = *(const bf16x8*)(ws + WQ + (16 + m) * 32 + k0);
  float bc0 = bq[m], bc1 = bq[16 + m];
  f32x4 q0[4], q1[4];
#pragma unroll
  for (int mt = 0; mt < 4; mt++) {
    f32x4 i0 = {bc0, bc0, bc0, bc0}, i1 = {bc1, bc1, bc1, bc1};
    q0[mt] = MFMA(hA[mt], wb0, i0);
    q1[mt] = MFMA(hA[mt], wb1, i1);
  }
#pragma unroll
  for (int mt = 0; mt < 4; mt++)
#pragma unroll
    for (int r = 0; r < 4; r++) { q0[mt][r] = phi(q0[mt][r]); q1[mt][r] = phi(q1[mt][r]); }
  // ---- attnraw = q @ kvmat (staged, packed-k)
  bf16x8 kb0 = *(const bf16x8*)(ws + KVM + m * 32 + k0);
  bf16x8 kb1 = *(const bf16x8*)(ws + KVM + (16 + m) * 32 + k0);
  f32x4 at0[4], at1[4];
#pragma unroll
  for (int mt = 0; mt < 4; mt++) {
#pragma unroll
    for (int r = 0; r < 4; r++)
      *(unsigned*)&mt_t[(quad * 4 + r) * 40 + 2 * m] = pkbf(q0[mt][r], q1[mt][r]);
    lds_fence();
    bf16x8 aq = *(const bf16x8*)(mt_t + m * 40 + k0);
    f32x4 zz = {0.f, 0.f, 0.f, 0.f};
    at0[mt] = MFMA(aq, kb0, zz);
    at1[mt] = MFMA(aq, kb1, zz);
    lds_fence();
  }
  // ---- z = 1/(q . ksum + eps), fp32
  {
    float ks0 = kvg[256 + m], ks1 = kvg[272 + m];
#pragma unroll
    for (int mt = 0; mt < 4; mt++)
#pragma unroll
      for (int r = 0; r < 4; r++) {
        float p0 = q0[mt][r] * ks0, p1 = q1[mt][r] * ks1;
        p0 += __shfl_xor(p0, 1); p0 += __shfl_xor(p0, 2); p0 += __shfl_xor(p0, 4);
        p1 += __shfl_xor(p1, 1); p1 += __shfl_xor(p1, 2); p1 += __shfl_xor(p1, 4);
        at0[mt][r] *= 1.f / (p0 + EPS_Z);
        at1[mt][r] *= 1.f / (p1 + EPS_Z);
      }
  }
  // ---- h += attn @ wo + bo
  wb0 = *(const bf16x8*)(ws + WO + m * 32 + k0);
  wb1 = *(const bf16x8*)(ws + WO + (16 + m) * 32 + k0);
  bc0 = bo[m]; bc1 = bo[16 + m];
#pragma unroll
  for (int mt = 0; mt < 4; mt++) {
#pragma unroll
    for (int r = 0; r < 4; r++)
      *(unsigned*)&mt_t[(quad * 4 + r) * 40 + 2 * m] = pkbf(at0[mt][r], at1[mt][r]);
    lds_fence();
    bf16x8 aa = *(const bf16x8*)(mt_t + m * 40 + k0);
    f32x4 i0 = hc0[mt], i1 = hc1[mt];
#pragma unroll
    for (int r = 0; r < 4; r++) { i0[r] += bc0; i1[r] += bc1; }
    hc0[mt] = MFMA(aa, wb0, i0);
    hc1[mt] = MFMA(aa, wb1, i1);
    lds_fence();
  }
  // ---- LN1
  {
    float gg0 = g1[m], gg1 = g1[16 + m], bb0 = be1[m], bb1 = be1[16 + m];
#pragma unroll
    for (int mt = 0; mt < 4; mt++) ln_c(hc0[mt], hc1[mt], gg0, gg1, bb0, bb1);
  }
  // ---- FFN
  bf16x8 w1f[4]; float b1c[4];
#pragma unroll
  for (int nt = 0; nt < 4; nt++) {
    w1f[nt] = *(const bf16x8*)(ws + W1 + (nt * 16 + m) * 32 + k0);
    b1c[nt] = bf1[nt * 16 + m];
  }
  bf16x8 w2f00 = *(const bf16x8*)(ws + W2 + m * 64 + k0);
  bf16x8 w2f01 = *(const bf16x8*)(ws + W2 + (16 + m) * 64 + k0);
  bf16x8 w2f10 = *(const bf16x8*)(ws + W2 + m * 64 + 32 + k0);
  bf16x8 w2f11 = *(const bf16x8*)(ws + W2 + (16 + m) * 64 + 32 + k0);
  float b2c0 = bf2[m], b2c1 = bf2[16 + m];
#pragma unroll
  for (int mt = 0; mt < 4; mt++) {
#pragma unroll
    for (int r = 0; r < 4; r++)
      *(unsigned*)&mt_t[(quad * 4 + r) * 40 + 2 * m] = pkbf(hc0[mt][r], hc1[mt][r]);
    lds_fence();
    bf16x8 ah = *(const bf16x8*)(mt_t + m * 40 + k0);
    f32x4 hd[4];
#pragma unroll
    for (int nt = 0; nt < 4; nt++) {
      f32x4 ini = {b1c[nt], b1c[nt], b1c[nt], b1c[nt]};
      hd[nt] = MFMA(ah, w1f[nt], ini);
    }
#pragma unroll
    for (int r = 0; r < 4; r++) {
      *(unsigned*)&hid_t[(quad * 4 + r) * 72 + 2 * m] =
          pkbf(fmaxf(hd[0][r], 0.f), fmaxf(hd[1][r], 0.f));
      *(unsigned*)&hid_t[(quad * 4 + r) * 72 + 32 + 2 * m] =
          pkbf(fmaxf(hd[2][r], 0.f), fmaxf(hd[3][r], 0.f));
    }
    lds_fence();
    bf16x8 a20 = *(const bf16x8*)(hid_t + m * 72 + k0);
    bf16x8 a21 = *(const bf16x8*)(hid_t + m * 72 + 32 + k0);
    f32x4 o0 = hc0[mt], o1 = hc1[mt];
#pragma unroll
    for (int r = 0; r < 4; r++) { o0[r] += b2c0; o1[r] += b2c1; }
    o0 = MFMA(a20, w2f00, o0);
    o0 = MFMA(a21, w2f10, o0);
    o1 = MFMA(a20, w2f01, o1);
    o1 = MFMA(a21, w2f11, o1);
    hc0[mt] = o0; hc1[mt] = o1;
    lds_fence();
  }
  // ---- LN2
  {
    float gg0 = g2[m], gg1 = g2[16 + m], bb0 = be2[m], bb1 = be2[16 + m];
#pragma unroll
    for (int mt = 0; mt < 4; mt++) ln_c(hc0[mt], hc1[mt], gg0, gg1, bb0, bb1);
  }
}

// kn = phi(h@wk+bk), vn = h@wv+bv; kv += kn^T@vn (per-head diag) via chunked
// feature-major staging (Tk/Tv 32x40 each, aliased over the per-wave tile region).
__device__ __forceinline__ void kv_stage(
    const f32x4* hc0, const f32x4* hc1, unsigned short* tw, const unsigned short* ws,
    int offk, int offv, float* blk, int quad, int m,
    const float* __restrict__ bk, const float* __restrict__ bv) {
  const int k0 = quad * 8;
  unsigned short* mt_t = tw;
  unsigned short* Tk = tw;           // alias: used only after ahf reads complete
  unsigned short* Tv = tw + 1280;
  bf16x8 ahf[4];
#pragma unroll
  for (int mt = 0; mt < 4; mt++) {
#pragma unroll
    for (int r = 0; r < 4; r++)
      *(unsigned*)&mt_t[(quad * 4 + r) * 40 + 2 * m] = pkbf(hc0[mt][r], hc1[mt][r]);
    lds_fence();
    ahf[mt] = *(const bf16x8*)(mt_t + m * 40 + k0);
    lds_fence();
  }
  bf16x8 wkb0 = *(const bf16x8*)(ws + offk + m * 32 + k0);
  bf16x8 wkb1 = *(const bf16x8*)(ws + offk + (16 + m) * 32 + k0);
  bf16x8 wvb0 = *(const bf16x8*)(ws + offv + m * 32 + k0);
  bf16x8 wvb1 = *(const bf16x8*)(ws + offv + (16 + m) * 32 + k0);
  float bk0 = bk[m], bk1 = bk[16 + m], bv0 = bv[m], bv1 = bv[16 + m];
  f32x4 accA = {0.f, 0.f, 0.f, 0.f}, accB = {0.f, 0.f, 0.f, 0.f};
  float s0 = 0.f, s1 = 0.f;
#pragma unroll
  for (int ch = 0; ch < 2; ch++) {
    f32x4 kn0[2], kn1[2], vn0[2], vn1[2];
#pragma unroll
    for (int mtl = 0; mtl < 2; mtl++) {
      int mt = ch * 2 + mtl;
      f32x4 ik0 = {bk0, bk0, bk0, bk0}, ik1 = {bk1, bk1, bk1, bk1};
      f32x4 iv0 = {bv0, bv0, bv0, bv0}, iv1 = {bv1, bv1, bv1, bv1};
      kn0[mtl] = MFMA(ahf[mt], wkb0, ik0);
      kn1[mtl] = MFMA(ahf[mt], wkb1, ik1);
      vn0[mtl] = MFMA(ahf[mt], wvb0, iv0);
      vn1[mtl] = MFMA(ahf[mt], wvb1, iv1);
#pragma unroll
      for (int r = 0; r < 4; r++) {
        kn0[mtl][r] = phi(kn0[mtl][r]); kn1[mtl][r] = phi(kn1[mtl][r]);
        s0 += kn0[mtl][r]; s1 += kn1[mtl][r];
      }
    }
    // feature-major staging: T[feat][pt], stride 40; pack r=0..3 (contiguous pts) -> b64
#pragma unroll
    for (int mtl = 0; mtl < 2; mtl++) {
      int pb = mtl * 16 + quad * 4;
      *(uint2*)(Tk + m * 40 + pb)        = make_uint2(pkbf(kn0[mtl][0], kn0[mtl][1]),
                                                      pkbf(kn0[mtl][2], kn0[mtl][3]));
      *(uint2*)(Tk + (16 + m) * 40 + pb) = make_uint2(pkbf(kn1[mtl][0], kn1[mtl][1]),
                                                      pkbf(kn1[mtl][2], kn1[mtl][3]));
      *(uint2*)(Tv + m * 40 + pb)        = make_uint2(pkbf(vn0[mtl][0], vn0[mtl][1]),
                                                      pkbf(vn0[mtl][2], vn0[mtl][3]));
      *(uint2*)(Tv + (16 + m) * 40 + pb) = make_uint2(pkbf(vn1[mtl][0], vn1[mtl][1]),
                                                      pkbf(vn1[mtl][2], vn1[mtl][3]));
    }
    lds_fence();
    bf16x8 ak0 = *(const bf16x8*)(Tk + m * 40 + k0);
    bf16x8 av0 = *(const bf16x8*)(Tv + m * 40 + k0);
    bf16x8 ak1 = *(const bf16x8*)(Tk + (16 + m) * 40 + k0);
    bf16x8 av1 = *(const bf16x8*)(Tv + (16 + m) * 40 + k0);
    accA = MFMA(ak0, av0, accA);   // feat-half 0 (heads 0,1)
    accB = MFMA(ak1, av1, accB);   // feat-half 1 (heads 2,3)
    lds_fence();
  }
  s0 += __shfl_xor(s0, 16); s0 += __shfl_xor(s0, 32);
  s1 += __shfl_xor(s1, 16); s1 += __shfl_xor(s1, 32);
  if (quad == 0) { atomicAdd(&blk[256 + m], s0); atomicAdd(&blk[272 + m], s1); }
  if ((quad >> 1) == (m >> 3)) {   // same-head diagonal blocks only
    int din = (quad & 1) * 4, ein = m & 7;
    int h0 = (quad >> 1), h1 = 2 + (quad >> 1);
#pragma unroll
    for (int r = 0; r < 4; r++) {
      atomicAdd(&blk[h0 * 64 + (din + r) * 8 + ein], accA[r]);
      atomicAdd(&blk[h1 * 64 + (din + r) * 8 + ein], accB[r]);
    }
  }
}

// K1: embed -> h0 (to d_out), layer-0 kn/vn -> kv accum
__global__ __launch_bounds__(256) void k_embed(
    const float* __restrict__ x, const float* __restrict__ pos,
    const float* __restrict__ w_in, const float* __restrict__ b_in,
    const float* __restrict__ w_pos, const float* __restrict__ b_pos,
    const float* __restrict__ wk, const float* __restrict__ bk,
    const float* __restrict__ wv, const float* __restrict__ bv,
    float* __restrict__ hout, float* __restrict__ gkv) {
  __shared__ __align__(16) unsigned short ws[3072];
  __shared__ __align__(16) unsigned short tiles[4 * 2560];
  __shared__ float blk[KVSZ];
  const int tid = threadIdx.x;
  const int wv_ = tid >> 6, lane = tid & 63, quad = lane >> 4, m = lane & 15;
  unsigned short* tw = tiles + wv_ * 2560;
  for (int i = tid; i < 1024; i += 256) {           // wE: identity k-order
    int n = i >> 5, k = i & 31;
    float v = k < 16 ? w_in[k * 32 + n] : (k < 19 ? w_pos[(k - 16) * 32 + n] : 0.f);
    ws[i] = f2bf(v);
  }
  stage_pk32(ws + 1024, wk, 32, tid);
  stage_pk32(ws + 2048, wv, 32, tid);
  for (int i = tid; i < KVSZ; i += 256) blk[i] = 0.f;
  __syncthreads();
  const int wbase = blockIdx.x * 256 + wv_ * 64;
  const int cloud = blockIdx.x >> 7;
  const int k0 = quad * 8;
  bf16x8 aE[4];
#pragma unroll
  for (int mt = 0; mt < 4; mt++) {
    int p = wbase + mt * 16 + m;
    bf16x8 a;
#pragma unroll
    for (int j = 0; j < 8; j++) a[j] = 0;
    if (quad < 2) {
      const float4* xp = (const float4*)(x + (size_t)p * 16 + quad * 8);
      float4 t0 = xp[0], t1 = xp[1];
      a[0] = f2bf(t0.x); a[1] = f2bf(t0.y); a[2] = f2bf(t0.z); a[3] = f2bf(t0.w);
      a[4] = f2bf(t1.x); a[5] = f2bf(t1.y); a[6] = f2bf(t1.z); a[7] = f2bf(t1.w);
    } else if (quad == 2) {
      const float* pp = pos + (size_t)p * 3;
      a[0] = f2bf(pp[0]); a[1] = f2bf(pp[1]); a[2] = f2bf(pp[2]);
    }
    aE[mt] = a;
  }
  bf16x8 we0 = *(const bf16x8*)(ws + m * 32 + k0);
  bf16x8 we1 = *(const bf16x8*)(ws + (16 + m) * 32 + k0);
  float bc0 = b_in[m] + b_pos[m], bc1 = b_in[16 + m] + b_pos[16 + m];
  f32x4 hc0[4], hc1[4];
#pragma unroll
  for (int mt = 0; mt < 4; mt++) {
    f32x4 i0 = {bc0, bc0, bc0, bc0}, i1 = {bc1, bc1, bc1, bc1};
    hc0[mt] = MFMA(aE[mt], we0, i0);
    hc1[mt] = MFMA(aE[mt], we1, i1);
  }
#pragma unroll
  for (int mt = 0; mt < 4; mt++)
#pragma unroll
    for (int r = 0; r < 4; r++) {
      int p = wbase + mt * 16 + quad * 4 + r;
      hout[(size_t)p * 32 + m]      = hc0[mt][r];
      hout[(size_t)p * 32 + 16 + m] = hc1[mt][r];
    }
  kv_stage(hc0, hc1, tw, ws, 1024, 2048, blk, quad, m, bk, bv);
  __syncthreads();
  float* g = gkv + cloud * KVSZ;
  for (int i = tid; i < KVSZ; i += 256) atomicAdd(&g[i], blk[i]);
}

// K2: layer-0 attn+FFN (in place on hbuf), layer-1 kn/vn -> kv accum
__global__ __launch_bounds__(256) void k_mid(
    const float* __restrict__ wq, const float* __restrict__ bq,
    const float* __restrict__ wo, const float* __restrict__ bo,
    const float* __restrict__ g1, const float* __restrict__ be1,
    const float* __restrict__ w1, const float* __restrict__ bf1,
    const float* __restrict__ w2, const float* __restrict__ bf2,
    const float* __restrict__ g2, const float* __restrict__ be2,
    const float* __restrict__ wkn, const float* __restrict__ bkn,
    const float* __restrict__ wvn, const float* __restrict__ bvn,
    const float* __restrict__ kv_in, float* __restrict__ gkv_out,
    float* __restrict__ hbuf) {
  __shared__ __align__(16) unsigned short ws[9216];
  __shared__ __align__(16) unsigned short tiles[4 * 2560];
  __shared__ float blk[KVSZ];
  const int tid = threadIdx.x;
  const int wv_ = tid >> 6, lane = tid & 63, quad = lane >> 4, m = lane & 15;
  unsigned short* tw = tiles + wv_ * 2560;
  const int cloud = blockIdx.x >> 7;
  stage_pk32(ws + WQ, wq, 32, tid);
  stage_pk32(ws + WO, wo, 32, tid);
  stage_kvm(ws + KVM, kv_in + cloud * KVSZ, tid);
  stage_pk32(ws + W1, w1, 64, tid);
  stage_pk64(ws + W2, w2, tid);
  stage_pk32(ws + WKN, wkn, 32, tid);
  stage_pk32(ws + WVN, wvn, 32, tid);
  for (int i = tid; i < KVSZ; i += 256) blk[i] = 0.f;
  __syncthreads();
  const int wbase = blockIdx.x * 256 + wv_ * 64;
  const int k0 = quad * 8;
  f32x4 hc0[4], hc1[4];
#pragma unroll
  for (int mt = 0; mt < 4; mt++)
#pragma unroll
    for (int r = 0; r < 4; r++) {
      int p = wbase + mt * 16 + quad * 4 + r;
      hc0[mt][r] = hbuf[(size_t)p * 32 + m];
      hc1[mt][r] = hbuf[(size_t)p * 32 + 16 + m];
    }
  bf16x8 hA[4];     // A-frags in packed k-order: slot j = logical (j&1)*16 + quad*4 + (j>>1)
#pragma unroll
  for (int mt = 0; mt < 4; mt++) {
    const float* hp = hbuf + (size_t)(wbase + mt * 16 + m) * 32;
    float4 lo = *(const float4*)(hp + quad * 4);
    float4 hi = *(const float4*)(hp + 16 + quad * 4);
    union { bf16x8 v; unsigned u[4]; } cv;
    cv.u[0] = pkbf(lo.x, hi.x); cv.u[1] = pkbf(lo.y, hi.y);
    cv.u[2] = pkbf(lo.z, hi.z); cv.u[3] = pkbf(lo.w, hi.w);
    hA[mt] = cv.v;
  }
  layer_core(hc0, hc1, hA, tw, ws, quad, m, bq, bo, g1, be1, bf1, bf2, g2, be2,
             kv_in + cloud * KVSZ);
#pragma unroll
  for (int mt = 0; mt < 4; mt++)
#pragma unroll
    for (int r = 0; r < 4; r++) {
      int p = wbase + mt * 16 + quad * 4 + r;
      hbuf[(size_t)p * 32 + m]      = hc0[mt][r];
      hbuf[(size_t)p * 32 + 16 + m] = hc1[mt][r];
    }
  kv_stage(hc0, hc1, tw, ws, WKN, WVN, blk, quad, m, bkn, bvn);
  __syncthreads();
  float* g = gkv_out + cloud * KVSZ;
  for (int i = tid; i < KVSZ; i += 256) atomicAdd(&g[i], blk[i]);
}

// K3: layer-1 attn+FFN -> final output (in place on hbuf == d_out)
__global__ __launch_bounds__(256) void k_last(
    const float* __restrict__ wq, const float* __restrict__ bq,
    const float* __restrict__ wo, const float* __restrict__ bo,
    const float* __restrict__ g1, const float* __restrict__ be1,
    const float* __restrict__ w1, const float* __restrict__ bf1,
    const float* __restrict__ w2, const float* __restrict__ bf2,
    const float* __restrict__ g2, const float* __restrict__ be2,
    const float* __restrict__ kv_in, float* __restrict__ hbuf) {
  __shared__ __align__(16) unsigned short ws[7168];
  __shared__ __align__(16) unsigned short tiles[4 * 2560];
  const int tid = threadIdx.x;
  const int wv_ = tid >> 6, lane = tid & 63, quad = lane >> 4, m = lane & 15;
  unsigned short* tw = tiles + wv_ * 2560;
  const int cloud = blockIdx.x >> 7;
  stage_pk32(ws + WQ, wq, 32, tid);
  stage_pk32(ws + WO, wo, 32, tid);
  stage_kvm(ws + KVM, kv_in + cloud * KVSZ, tid);
  stage_pk32(ws + W1, w1, 64, tid);
  stage_pk64(ws + W2, w2, tid);
  __syncthreads();
  const int wbase = blockIdx.x * 256 + wv_ * 64;
  const int k0 = quad * 8;
  f32x4 hc0[4], hc1[4];
#pragma unroll
  for (int mt = 0; mt < 4; mt++)
#pragma unroll
    for (int r = 0; r < 4; r++) {
      int p = wbase + mt * 16 + quad * 4 + r;
      hc0[mt][r] = hbuf[(size_t)p * 32 + m];
      hc1[mt][r] = hbuf[(size_t)p * 32 + 16 + m];
    }
  bf16x8 hA[4];
#pragma unroll
  for (int mt = 0; mt < 4; mt++) {
    const float* hp = hbuf + (size_t)(wbase + mt * 16 + m) * 32;
    float4 lo = *(const float4*)(hp + quad * 4);
    float4 hi = *(const float4*)(hp + 16 + quad * 4);
    union { bf16x8 v; unsigned u[4]; } cv;
    cv.u[0] = pkbf(lo.x, hi.x); cv.u[1] = pkbf(lo.y, hi.y);
    cv.u[2] = pkbf(lo.z, hi.z); cv.u[3] = pkbf(lo.w, hi.w);
    hA[mt] = cv.v;
  }
  layer_core(hc0, hc1, hA, tw, ws, quad, m, bq, bo, g1, be1, bf1, bf2, g2, be2,
             kv_in + cloud * KVSZ);
#pragma unroll
  for (int mt = 0; mt < 4; mt++)
#pragma unroll
    for (int r = 0; r < 4; r++) {
      int p = wbase + mt * 16 + quad * 4 + r;
      hbuf[(size_t)p * 32 + m]      = hc0[mt][r];
      hbuf[(size_t)p * 32 + 16 + m] = hc1[mt][r];
    }
}

extern "C" void kernel_launch(void* const* d_in, const int* in_sizes, int n_in,
                              void* d_out, int out_size, void* d_ws, size_t ws_size,
                              hipStream_t stream) {
  (void)in_sizes; (void)n_in; (void)out_size; (void)ws_size;
  const float* x     = (const float*)d_in[0];
  const float* pos   = (const float*)d_in[1];
  // d_in[2] = batch (arange // N_PER): identity mapping, unused
  const float* w_in  = (const float*)d_in[3];
  const float* b_in  = (const float*)d_in[4];
  const float* w_pos = (const float*)d_in[5];
  const float* b_pos = (const float*)d_in[6];
  const float* wq  = (const float*)d_in[7];
  const float* bq  = (const float*)d_in[8];
  const float* wk  = (const float*)d_in[9];
  const float* bk  = (const float*)d_in[10];
  const float* wv  = (const float*)d_in[11];
  const float* bv  = (const float*)d_in[12];
  const float* wo  = (const float*)d_in[13];
  const float* bo  = (const float*)d_in[14];
  const float* g1  = (const float*)d_in[15];
  const float* be1 = (const float*)d_in[16];
  const float* w1  = (const float*)d_in[17];
  const float* bf1 = (const float*)d_in[18];
  const float* w2  = (const float*)d_in[19];
  const float* bf2 = (const float*)d_in[20];
  const float* g2  = (const float*)d_in[21];
  const float* be2 = (const float*)d_in[22];
  float* out   = (float*)d_out;
  float* kvbuf = (float*)d_ws;   // 2 layers * 16 clouds * 288 floats

  hipMemsetAsync(kvbuf, 0, 2 * 16 * KVSZ * sizeof(float), stream);
  dim3 grid(2048), block(256);
  k_embed<<<grid, block, 0, stream>>>(x, pos, w_in, b_in, w_pos, b_pos,
                                      wk, bk, wv, bv, out, kvbuf);
  k_mid<<<grid, block, 0, stream>>>(wq, bq, wo, bo, g1, be1, w1, bf1, w2, bf2, g2, be2,
                                    wk + 1024, bk + 32, wv + 1024, bv + 32,
                                    kvbuf, kvbuf + 16 * KVSZ, out);
  k_last<<<grid, block, 0, stream>>>(wq + 1024, bq + 32, wo + 1024, bo + 32,
                                     g1 + 32, be1 + 32, w1 + 2048, bf1 + 64,
                                     w2 + 2048, bf2 + 32, g2 + 32, be2 + 32,
                                     kvbuf + 16 * KVSZ, out);
}